// Round 4
// baseline (21.926 us; speedup 1.0000x reference)
//
#include <hip/hip_runtime.h>

// Problem constants (setup_inputs: [16,3,512,512] f32, patch 16)
#define N_   16
#define C_   3
#define H_   512
#define W_   512
#define P_   16
#define HP_  (H_ / P_)    // 32
#define WP_  (W_ / P_)    // 32
#define NC_  (N_ * C_)    // 48
#define NBLK_ (NC_ * HP_) // 1536

// One block per (n, c, hp) strip: 16 rows x 512 cols = 2048 float4 per input.
// 512 threads x 4 iters; thread t always reads col4 = t%128 -> fixed wp.
// Plain store of strip max into ws[hp*NC_+nc]; no atomics, no init.
__global__ __launch_bounds__(512) void pl_strips(const float* __restrict__ outp,
                                                 const float* __restrict__ tgtp,
                                                 float* __restrict__ ws) {
    const int b  = blockIdx.x;       // (n*C + c)*HP + hp
    const int hp = b % HP_;
    const int nc = b / HP_;
    const int t  = threadIdx.x;

    const long long base4 = ((long long)nc * H_ + (long long)hp * P_) * (W_ / 4);
    const float4* __restrict__ o4 = (const float4*)outp + base4;
    const float4* __restrict__ t4 = (const float4*)tgtp + base4;

    // Issue all 8 loads up front (independent), then consume.
    float4 a[4], c[4];
#pragma unroll
    for (int i = 0; i < 4; ++i) a[i] = o4[i * 512 + t];
#pragma unroll
    for (int i = 0; i < 4; ++i) c[i] = t4[i * 512 + t];

    float s = 0.0f;
#pragma unroll
    for (int i = 0; i < 4; ++i) {
        s += fabsf(a[i].x - c[i].x) + fabsf(a[i].y - c[i].y) +
             fabsf(a[i].z - c[i].z) + fabsf(a[i].w - c[i].w);
    }

    // idx = i*512+t: row = idx/128 = 4i + t/128, col4 = t%128 (fixed).
    // lanes {4g..4g+3} share one wp = (t%128)/4.
    s += __shfl_xor(s, 1);
    s += __shfl_xor(s, 2);

    __shared__ float gsum[128];          // group g: wp = g%32, rowset = g/32
    if ((t & 3) == 0) gsum[t >> 2] = s;
    __syncthreads();

    if (t < 32) {
        // sum the 4 rowsets (each read conflict-free: bank = lane), patch mean
        float v = (gsum[t] + gsum[t + 32] + gsum[t + 64] + gsum[t + 96])
                  * (1.0f / (P_ * P_));
        for (int off = 16; off >= 1; off >>= 1)
            v = fmaxf(v, __shfl_xor(v, off));   // max over 32 wp
        if (t == 0) ws[hp * NC_ + nc] = v;      // plain store
    }
}

// One block: reduce 1536 strip-maxes -> 48 per-(n,c) maxes -> mean -> scalar.
__global__ __launch_bounds__(256) void pl_finalize(const float* __restrict__ ws,
                                                   float* __restrict__ res) {
    __shared__ float sm[NBLK_];
    const int t = threadIdx.x;  // 256
#pragma unroll
    for (int i = 0; i < NBLK_ / 256; ++i) sm[t + i * 256] = ws[t + i * 256];
    __syncthreads();

    float v = 0.0f;  // matches reference's max(., 0) seed; losses >= 0
    if (t < NC_) {
        // transposed layout: sm[hp*NC_ + t] -> bank varies with t, conflict-free
        for (int hp = 0; hp < HP_; ++hp)
            v = fmaxf(v, sm[hp * NC_ + t]);
    }
    if (t < 64) {  // threads 0..47 live in wave 0; lanes 48..63 contribute 0
#pragma unroll
        for (int off = 32; off >= 1; off >>= 1)
            v += __shfl_xor(v, off);
        if (t == 0) res[0] = v * (1.0f / NC_);
    }
}

extern "C" void kernel_launch(void* const* d_in, const int* in_sizes, int n_in,
                              void* d_out, int out_size, void* d_ws, size_t ws_size,
                              hipStream_t stream) {
    const float* outp = (const float*)d_in[0];
    const float* tgtp = (const float*)d_in[1];
    float* res = (float*)d_out;
    float* ws  = (float*)d_ws;   // NBLK_ floats

    pl_strips<<<NBLK_, 512, 0, stream>>>(outp, tgtp, ws);
    pl_finalize<<<1, 256, 0, stream>>>(ws, res);
}

// Round 6
// 19.319 us; speedup vs baseline: 1.1349x; 1.1349x over previous
//
#include <hip/hip_runtime.h>

// Problem constants (setup_inputs: [16,3,512,512] f32, patch 16)
#define N_   16
#define C_   3
#define H_   512
#define W_   512
#define P_   16
#define HP_  (H_ / P_)    // 32
#define WP_  (W_ / P_)    // 32
#define NC_  (N_ * C_)    // 48
#define NBLK_ (NC_ * HP_) // 1536

// native clang vector type: __builtin_nontemporal_load requires it
typedef float vfloat4 __attribute__((ext_vector_type(4)));

// One block per (n, c, hp) strip: 16 rows x 512 cols = 2048 float4 per input.
// 256 threads x 8 iters; thread t always reads col4 = t%128 -> fixed wp.
// Non-temporal loads: pure streaming, no reuse -> don't thrash L2.
__global__ __launch_bounds__(256) void pl_strips(const float* __restrict__ outp,
                                                 const float* __restrict__ tgtp,
                                                 float* __restrict__ ws) {
    const int b  = blockIdx.x;       // (n*C + c)*HP + hp
    const int hp = b % HP_;
    const int nc = b / HP_;
    const int t  = threadIdx.x;

    const long long base4 = ((long long)nc * H_ + (long long)hp * P_) * (W_ / 4);
    const vfloat4* __restrict__ o4 = (const vfloat4*)outp + base4;
    const vfloat4* __restrict__ t4 = (const vfloat4*)tgtp + base4;

    // Issue all 16 loads up front (independent), nt-hinted.
    vfloat4 a[8], c[8];
#pragma unroll
    for (int i = 0; i < 8; ++i) a[i] = __builtin_nontemporal_load(&o4[i * 256 + t]);
#pragma unroll
    for (int i = 0; i < 8; ++i) c[i] = __builtin_nontemporal_load(&t4[i * 256 + t]);

    float s = 0.0f;
#pragma unroll
    for (int i = 0; i < 8; ++i) {
        s += fabsf(a[i].x - c[i].x) + fabsf(a[i].y - c[i].y) +
             fabsf(a[i].z - c[i].z) + fabsf(a[i].w - c[i].w);
    }

    // idx = i*256+t: row = idx/128, col4 = t%128 (fixed) -> wp = (t%128)/4.
    // lanes {4g..4g+3} share one wp.
    s += __shfl_xor(s, 1);
    s += __shfl_xor(s, 2);

    __shared__ float gsum[64];
    if ((t & 3) == 0) gsum[t >> 2] = s;
    __syncthreads();

    if (t < 32) {
        float v = (gsum[t] + gsum[t + 32]) * (1.0f / (P_ * P_)); // patch mean
        for (int off = 16; off >= 1; off >>= 1)
            v = fmaxf(v, __shfl_xor(v, off));                    // max over 32 wp
        if (t == 0) ws[hp * NC_ + nc] = v;                       // plain store
    }
}

// One block: reduce 1536 strip-maxes -> 48 per-(n,c) maxes -> mean -> scalar.
__global__ __launch_bounds__(256) void pl_finalize(const float* __restrict__ ws,
                                                   float* __restrict__ res) {
    __shared__ float sm[NBLK_];
    const int t = threadIdx.x;  // 256
#pragma unroll
    for (int i = 0; i < NBLK_ / 256; ++i) sm[t + i * 256] = ws[t + i * 256];
    __syncthreads();

    float v = 0.0f;  // matches reference's max(., 0) seed; losses >= 0
    if (t < NC_) {
        // transposed layout: sm[hp*NC_ + t] -> bank varies with t, conflict-free
        for (int hp = 0; hp < HP_; ++hp)
            v = fmaxf(v, sm[hp * NC_ + t]);
    }
    if (t < 64) {  // threads 0..47 live in wave 0; lanes 48..63 contribute 0
#pragma unroll
        for (int off = 32; off >= 1; off >>= 1)
            v += __shfl_xor(v, off);
        if (t == 0) res[0] = v * (1.0f / NC_);
    }
}

extern "C" void kernel_launch(void* const* d_in, const int* in_sizes, int n_in,
                              void* d_out, int out_size, void* d_ws, size_t ws_size,
                              hipStream_t stream) {
    const float* outp = (const float*)d_in[0];
    const float* tgtp = (const float*)d_in[1];
    float* res = (float*)d_out;
    float* ws  = (float*)d_ws;   // NBLK_ floats

    pl_strips<<<NBLK_, 256, 0, stream>>>(outp, tgtp, ws);
    pl_finalize<<<1, 256, 0, stream>>>(ws, res);
}